// Round 14
// baseline (74.759 us; speedup 1.0000x reference)
//
#include <hip/hip_runtime.h>

typedef unsigned short u16;
typedef unsigned int u32;
typedef __bf16 bf16x8 __attribute__((ext_vector_type(8)));
typedef unsigned short ushort8 __attribute__((ext_vector_type(8)));
typedef float f32x4 __attribute__((ext_vector_type(4)));

#define DEV_INLINE __device__ __forceinline__

constexpr int NB = 4;
constexpr int NAG = 4096;
constexpr int ROWS = NB * NAG;
constexpr int GRID = 20;
constexpr int CELLS = GRID * GRID;
constexpr int CSTRIDE = 404;

DEV_INLINE u16 f2bu(float x) { __bf16 h = (__bf16)x; return __builtin_bit_cast(u16, h); }
DEV_INLINE u32 pack2(float a, float b) { return (u32)f2bu(a) | ((u32)f2bu(b) << 16); }

DEV_INLINE f32x4 MF(bf16x8 a, const u16* p, f32x4 c) {
  ushort8 bu = *(const ushort8*)p;
  return __builtin_amdgcn_mfma_f32_16x16x32_bf16(a, __builtin_bit_cast(bf16x8, bu), c, 0, 0, 0);
}
DEV_INLINE f32x4 MFv(bf16x8 a, ushort8 bu, f32x4 c) {
  return __builtin_amdgcn_mfma_f32_16x16x32_bf16(a, __builtin_bit_cast(bf16x8, bu), c, 0, 0, 0);
}

template<bool BF>
DEV_INLINE bf16x8 loadA(const void* __restrict__ src, int row, int c) {
  if constexpr (BF) {
    ushort8 u = *reinterpret_cast<const ushort8*>((const u16*)src + (size_t)row * 64 + c);
    return __builtin_bit_cast(bf16x8, u);
  } else {
    const float* f = (const float*)src + (size_t)row * 64 + c;
    f32x4 a = *(const f32x4*)f;
    f32x4 b = *(const f32x4*)(f + 4);
    bf16x8 r;
    r[0] = (__bf16)a[0]; r[1] = (__bf16)a[1]; r[2] = (__bf16)a[2]; r[3] = (__bf16)a[3];
    r[4] = (__bf16)b[0]; r[5] = (__bf16)b[1]; r[6] = (__bf16)b[2]; r[7] = (__bf16)b[3];
    return r;
  }
}

// ================= K0: binning only (4 blocks x 1024) — also emits invp (orig -> local sorted)
__global__ __launch_bounds__(1024) void bin_kernel(
    const float* __restrict__ pos, float2* __restrict__ pos_sorted,
    int* __restrict__ cell_start, int* __restrict__ sid, int* __restrict__ invp)
{
  __shared__ int cnt_s[CELLS];
  __shared__ int start_s[CELLS + 1];
  __shared__ u16 cell_of[NAG];
  __shared__ u16 rank_of[NAG];
  const int tid = threadIdx.x;
  const int lane = tid & 63;
  const int wave = tid >> 6;
  const int bid = blockIdx.x;
  const float2* pb = (const float2*)(pos + (size_t)bid * NAG * 2);
  for (int c = tid; c < CELLS; c += 1024) cnt_s[c] = 0;
  __syncthreads();
  for (int i = tid; i < NAG; i += 1024) {
    float2 p = pb[i];
    int cx = min(max((int)floorf(p.x), 0), GRID - 1);
    int cy = min(max((int)floorf(p.y), 0), GRID - 1);
    int c = cy * GRID + cx;
    rank_of[i] = (u16)atomicAdd(&cnt_s[c], 1);
    cell_of[i] = (u16)c;
  }
  __syncthreads();
  if (wave == 0) {
    int carry = 0;
    for (int g = 0; g < CELLS; g += 64) {
      int c = g + lane;
      int x = (c < CELLS) ? cnt_s[c] : 0;
#pragma unroll
      for (int off = 1; off < 64; off <<= 1) {
        int y = __shfl_up(x, off, 64);
        if (lane >= off) x += y;
      }
      if (c < CELLS) start_s[c + 1] = carry + x;
      carry += __shfl(x, 63, 64);
    }
    if (lane == 0) start_s[0] = 0;
  }
  __syncthreads();
  for (int c = tid; c <= CELLS; c += 1024) cell_start[bid * CSTRIDE + c] = start_s[c];
  for (int i = tid; i < NAG; i += 1024) {
    int kk = start_s[cell_of[i]] + (int)rank_of[i];
    sid[bid * NAG + kk] = bid * NAG + i;     // global orig row
    invp[bid * NAG + i] = kk;                // LOCAL sorted index
    pos_sorted[bid * NAG + kk] = pb[i];
  }
}

// ================= K1: mlp1 (blocks 0..255) | W3-6 transpose (256..259)
// wts layout (u16): W3T[128n][128k]@0, W4T[64n][128k]@16384, W5T[128n][128k]@24576, W6T[64n][128k]@40960.
// msgs: [ROWS][64] orig-order; msgsT: [NB][64ch][NAG] channel-major SORTED order.
__global__ __launch_bounds__(1024) void mlp1_kernel(
    const float* __restrict__ states,
    const float* __restrict__ W1, const float* __restrict__ b1,
    const float* __restrict__ W2, const float* __restrict__ b2,
    const float* __restrict__ W3, const float* __restrict__ W4,
    const float* __restrict__ W5, const float* __restrict__ W6,
    const int* __restrict__ invp,
    u16* __restrict__ wts, u16* __restrict__ msgs, u16* __restrict__ msgsT)
{
  extern __shared__ u16 smem[];
  const int tid = threadIdx.x;
  const int lane = tid & 63;
  const int wave = tid >> 6;
  const int bid = blockIdx.x;

  if (bid >= 256) {
    const int base = (bid - 256) * 12288;
#pragma unroll
    for (int t = 0; t < 12; ++t) {
      int idx = base + t * 1024 + tid;
      const float* src; int n, k, Nc;
      if (idx < 16384)      { src = W3; n = idx >> 7; k = idx & 127; Nc = 128; }
      else if (idx < 24576) { int li = idx - 16384; src = W4; n = li >> 7; k = li & 127; Nc = 64; }
      else if (idx < 40960) { int li = idx - 24576; src = W5; n = li >> 7; k = li & 127; Nc = 128; }
      else                  { int li = idx - 40960; src = W6; n = li >> 7; k = li & 127; Nc = 64; }
      wts[idx] = f2bu(src[k * Nc + n]);
    }
    return;
  }

  u16* WaTs = smem;              // [128][72]
  u16* WbTs = smem + 9216;       // [64][136]
  u16* ovl  = smem + 17920;      // overlay

  const int l15 = lane & 15;
  const int khalf = (lane >> 4) * 8;
  const int rg = wave >> 2;
  const int cq = wave & 3;
  const int rb = bid * 64 + rg * 16;
  const int row = rb + l15;

  bf16x8 aS[2];
  aS[0] = loadA<false>(states, row, khalf);
  aS[1] = loadA<false>(states, row, 32 + khalf);

  for (int t = tid; t < 4096; t += 1024) {
    const int e = t * 2;
    const int k = e >> 7, n = e & 127;
    const float2 v = *(const float2*)&W1[e];
    *(u32*)&ovl[k * 132 + n] = pack2(v.x, v.y);
  }
  __syncthreads();
  {
    const int n = tid & 127, g = tid >> 7;
    ushort8 v;
#pragma unroll
    for (int j = 0; j < 8; ++j) v[j] = ovl[(g * 8 + j) * 132 + n];
    *(ushort8*)&WaTs[n * 72 + g * 8] = v;
  }
  __syncthreads();
  for (int t = tid; t < 4096; t += 1024) {
    const int e = t * 2;
    const int k = e >> 6, n = e & 63;
    const float2 v = *(const float2*)&W2[e];
    *(u32*)&ovl[k * 68 + n] = pack2(v.x, v.y);
  }
  __syncthreads();
  {
    const int n = tid & 63, g = tid >> 6;
    ushort8 v;
#pragma unroll
    for (int j = 0; j < 8; ++j) v[j] = ovl[(g * 8 + j) * 68 + n];
    *(ushort8*)&WbTs[n * 136 + g * 8] = v;
  }
  __syncthreads();

  u16* hs = ovl + rg * 2176;

  f32x4 acc1[2] = {};
#pragma unroll
  for (int kt = 0; kt < 2; ++kt) {
#pragma unroll
    for (int j = 0; j < 2; ++j) {
      const int nt = cq * 2 + j;
      acc1[j] = MF(aS[kt], &WaTs[(nt * 16 + l15) * 72 + kt * 32 + khalf], acc1[j]);
    }
  }
#pragma unroll
  for (int j = 0; j < 2; ++j) {
    const int col = (cq * 2 + j) * 16 + l15;
    const float bv = b1[col];
#pragma unroll
    for (int r = 0; r < 4; ++r)
      hs[((lane >> 4) * 4 + r) * 136 + col] = f2bu(fmaxf(acc1[j][r] + bv, 0.0f));
  }
  __syncthreads();

  f32x4 acc2 = {};
#pragma unroll
  for (int kt = 0; kt < 4; ++kt) {
    ushort8 au = *(const ushort8*)&hs[l15 * 136 + kt * 32 + khalf];
    acc2 = MF(__builtin_bit_cast(bf16x8, au),
              &WbTs[(cq * 16 + l15) * 136 + kt * 32 + khalf], acc2);
  }
  {
    const int col = cq * 16 + l15;
    const float bv = b2[col];
#pragma unroll
    for (int r = 0; r < 4; ++r) {
      const int grow = rb + (lane >> 4) * 4 + r;
      const u16 v = f2bu(acc2[r] + bv);
      msgs[(size_t)grow * 64 + col] = v;                 // orig-order (for K3)
      const int bb = grow >> 12;
      const int sl = invp[grow];                         // local sorted index
      msgsT[((size_t)(bb * 64 + col)) * NAG + sl] = v;   // channel-major sorted (for K2)
    }
  }
}

// ================= K2: MFMA aggregation — 16 sorted agents per wave.
// A[16 agents][K cands] built in-register from distance tests (bf16 1/0);
// B = msgsT channel-major sorted (ushort8 contiguous loads). D += A@B over
// candidate chunks of 32. Degree via per-lane count + butterfly. Epilogue
// repacks through LDS and stores orig-order rows (16B segments).
__global__ __launch_bounds__(256) void agg_kernel(
    const float2* __restrict__ pos_sorted, const u16* __restrict__ msgsT,
    const int* __restrict__ cell_start, const int* __restrict__ sid,
    const int* __restrict__ radius_ptr, u16* __restrict__ aggr)
{
  __shared__ u16 dsr[4][16][72];
  const int b = blockIdx.y;
  const int lane = threadIdx.x & 63;
  const int wave = threadIdx.x >> 6;
  const int l15 = lane & 15;
  const int grp = lane >> 4;
  const int khalf = grp * 8;
  const int k0 = (blockIdx.x * 4 + wave) * 16;       // first sorted agent of tile
  const int ks = k0 + l15;                           // this lane's agent (sorted local)
  const float2* pk = pos_sorted + (size_t)b * NAG;
  const int* cs = cell_start + b * CSTRIDE;
  const int* sb = sid + b * NAG;
  const float r = (float)(*radius_ptr);
  const float r2 = __fmul_rn(r, r);

  const float2 apos = pk[ks];
  int cx = min(max((int)floorf(apos.x), 0), GRID - 1);
  int cy = min(max((int)floorf(apos.y), 0), GRID - 1);
  int cxmin = cx, cxmax = cx, cymin = cy, cymax = cy;
#pragma unroll
  for (int off = 1; off < 16; off <<= 1) {
    cxmin = min(cxmin, __shfl_xor(cxmin, off));
    cxmax = max(cxmax, __shfl_xor(cxmax, off));
    cymin = min(cymin, __shfl_xor(cymin, off));
    cymax = max(cymax, __shfl_xor(cymax, off));
  }
  const int y0 = max(cymin - 1, 0), y1 = min(cymax + 1, GRID - 1);
  const int x0 = max(cxmin - 1, 0), x1 = min(cxmax + 1, GRID - 1);

  // per-lane B row pointers (channel = nt*16 + l15)
  const u16* bp0 = msgsT + ((size_t)(b * 64 + 0  + l15)) * NAG;
  const u16* bp1 = msgsT + ((size_t)(b * 64 + 16 + l15)) * NAG;
  const u16* bp2 = msgsT + ((size_t)(b * 64 + 32 + l15)) * NAG;
  const u16* bp3 = msgsT + ((size_t)(b * 64 + 48 + l15)) * NAG;

  const __bf16 one = (__bf16)1.0f;
  const __bf16 zero = (__bf16)0.0f;
  f32x4 acc[4] = {};
  int cnt = 0;

  for (int yy = y0; yy <= y1; ++yy) {
    const int c0 = cs[yy * GRID + x0];
    const int c1 = cs[yy * GRID + x1 + 1];
    for (int cc = c0; cc < c1; cc += 32) {
      const int cb = cc + khalf;
      // 8 candidate positions (vectorized; index-masked below so overrun is safe)
      const float4* pp = (const float4*)(pk + cb);
      const float4 q0 = pp[0], q1 = pp[1], q2 = pp[2], q3 = pp[3];
      float px[8], py[8];
      px[0] = q0.x; py[0] = q0.y; px[1] = q0.z; py[1] = q0.w;
      px[2] = q1.x; py[2] = q1.y; px[3] = q1.z; py[3] = q1.w;
      px[4] = q2.x; py[4] = q2.y; px[5] = q2.z; py[5] = q2.w;
      px[6] = q3.x; py[6] = q3.y; px[7] = q3.z; py[7] = q3.w;
      bf16x8 af;
#pragma unroll
      for (int j = 0; j < 8; ++j) {
        const int c = cb + j;
        const float dx_ = apos.x - px[j];
        const float dy_ = apos.y - py[j];
        const float d2 = __fadd_rn(__fmul_rn(dx_, dx_), __fmul_rn(dy_, dy_));
        const bool ok = (d2 < r2) && (c != ks) && (c < c1);
        af[j] = ok ? one : zero;
        cnt += ok ? 1 : 0;
      }
      acc[0] = MFv(af, *(const ushort8*)(bp0 + cb), acc[0]);
      acc[1] = MFv(af, *(const ushort8*)(bp1 + cb), acc[1]);
      acc[2] = MFv(af, *(const ushort8*)(bp2 + cb), acc[2]);
      acc[3] = MFv(af, *(const ushort8*)(bp3 + cb), acc[3]);
    }
  }

  // degree: sum the 4 k-slices of agent l15
  cnt += __shfl_xor(cnt, 16);
  cnt += __shfl_xor(cnt, 32);
  const float inv = 1.0f / (float)(cnt > 0 ? cnt : 1);
  float invr[4];
#pragma unroll
  for (int rr = 0; rr < 4; ++rr) invr[rr] = __shfl(inv, grp * 4 + rr);

  // repack D (row = grp*4+r, col = nt*16+l15) -> LDS -> coalesced orig-order store
#pragma unroll
  for (int nt = 0; nt < 4; ++nt)
#pragma unroll
    for (int rr = 0; rr < 4; ++rr)
      dsr[wave][grp * 4 + rr][nt * 16 + l15] = f2bu(acc[nt][rr] * invr[rr]);
  __syncthreads();

  const int orow = sb[k0 + (lane >> 2)];   // global orig row
  const int part = lane & 3;
  ushort8 v0 = *(const ushort8*)&dsr[wave][lane >> 2][part * 16];
  ushort8 v1 = *(const ushort8*)&dsr[wave][lane >> 2][part * 16 + 8];
  *(ushort8*)(aggr + (size_t)orow * 64 + part * 16) = v0;
  *(ushort8*)(aggr + (size_t)orow * 64 + part * 16 + 8) = v1;
}

// ================= K3: fused MLP2+MLP3 (verbatim from round 9/11)
__global__ __launch_bounds__(1024, 4) void mlp23_kernel(
    const float* __restrict__ states, const u16* __restrict__ msgs,
    const u16* __restrict__ aggr, const u16* __restrict__ wts,
    const float* __restrict__ b3, const float* __restrict__ b4,
    const float* __restrict__ b5, const float* __restrict__ b6,
    float* __restrict__ out)
{
  extern __shared__ u16 smem[];
  u16* W3s = smem;
  u16* W4s = W3s + 128 * 136;
  u16* W5s = W4s + 64 * 136;
  u16* W6s = W5s + 128 * 136;
  u16* hsb = W6s + 64 * 136;
  u16* fsb = hsb + 4 * 16 * 136;

  const int tid = threadIdx.x;
  const int lane = tid & 63;
  const int wave = tid >> 6;
  const int rg = wave >> 2;
  const int cq = wave & 3;
  const int l15 = lane & 15;
  const int khalf = (lane >> 4) * 8;
  const int rb = blockIdx.x * 64 + rg * 16;
  const int row = rb + l15;
  u16* hs = hsb + rg * (16 * 136);
  u16* fs = fsb + rg * (16 * 136);

  bf16x8 aM[2], aG[2], aS[2];
  aM[0] = loadA<true>(msgs, row, khalf);
  aM[1] = loadA<true>(msgs, row, 32 + khalf);
  aG[0] = loadA<true>(aggr, row, khalf);
  aG[1] = loadA<true>(aggr, row, 32 + khalf);
  aS[0] = loadA<false>(states, row, khalf);
  aS[1] = loadA<false>(states, row, 32 + khalf);

  for (int t = tid; t < 6144; t += 1024) {
    const int e = t * 8;
    ushort8 v = *(const ushort8*)&wts[e];
    u16* dst;
    if (e < 16384)      dst = &W3s[(e >> 7) * 136 + (e & 127)];
    else if (e < 24576) { int li = e - 16384; dst = &W4s[(li >> 7) * 136 + (li & 127)]; }
    else if (e < 40960) { int li = e - 24576; dst = &W5s[(li >> 7) * 136 + (li & 127)]; }
    else                { int li = e - 40960; dst = &W6s[(li >> 7) * 136 + (li & 127)]; }
    *(ushort8*)dst = v;
  }
  __syncthreads();

  f32x4 acc1[2] = {};
#pragma unroll
  for (int kt = 0; kt < 4; ++kt) {
    bf16x8 a = (kt < 2) ? aM[kt] : aG[kt - 2];
#pragma unroll
    for (int j = 0; j < 2; ++j) {
      const int nt = cq * 2 + j;
      acc1[j] = MF(a, &W3s[(nt * 16 + l15) * 136 + kt * 32 + khalf], acc1[j]);
    }
  }
#pragma unroll
  for (int j = 0; j < 2; ++j) {
    const int col = (cq * 2 + j) * 16 + l15;
    const float bv = b3[col];
#pragma unroll
    for (int r = 0; r < 4; ++r)
      hs[((lane >> 4) * 4 + r) * 136 + col] = f2bu(fmaxf(acc1[j][r] + bv, 0.0f));
  }
  __syncthreads();

  f32x4 acc2 = {};
#pragma unroll
  for (int kt = 0; kt < 4; ++kt) {
    ushort8 au = *(const ushort8*)&hs[l15 * 136 + kt * 32 + khalf];
    acc2 = MF(__builtin_bit_cast(bf16x8, au),
              &W4s[(cq * 16 + l15) * 136 + kt * 32 + khalf], acc2);
  }
  {
    const int col = cq * 16 + l15;
    const float bv = b4[col];
#pragma unroll
    for (int r = 0; r < 4; ++r)
      fs[((lane >> 4) * 4 + r) * 136 + col] = f2bu(acc2[r] + bv);
  }
  __syncthreads();

  f32x4 acc3[2] = {};
#pragma unroll
  for (int kt = 0; kt < 4; ++kt) {
    bf16x8 a;
    if (kt < 2) a = aS[kt];
    else {
      ushort8 au = *(const ushort8*)&fs[l15 * 136 + (kt - 2) * 32 + khalf];
      a = __builtin_bit_cast(bf16x8, au);
    }
#pragma unroll
    for (int j = 0; j < 2; ++j) {
      const int nt = cq * 2 + j;
      acc3[j] = MF(a, &W5s[(nt * 16 + l15) * 136 + kt * 32 + khalf], acc3[j]);
    }
  }
#pragma unroll
  for (int j = 0; j < 2; ++j) {
    const int col = (cq * 2 + j) * 16 + l15;
    const float bv = b5[col];
#pragma unroll
    for (int r = 0; r < 4; ++r)
      hs[((lane >> 4) * 4 + r) * 136 + col] = f2bu(fmaxf(acc3[j][r] + bv, 0.0f));
  }
  __syncthreads();

  f32x4 acc4 = {};
#pragma unroll
  for (int kt = 0; kt < 4; ++kt) {
    ushort8 au = *(const ushort8*)&hs[l15 * 136 + kt * 32 + khalf];
    acc4 = MF(__builtin_bit_cast(bf16x8, au),
              &W6s[(cq * 16 + l15) * 136 + kt * 32 + khalf], acc4);
  }
  {
    const int col = cq * 16 + l15;
    const float bv = b6[col];
#pragma unroll
    for (int r = 0; r < 4; ++r) {
      const int m = (lane >> 4) * 4 + r;
      const size_t o = (size_t)(rb + m) * 64 + col;
      out[o] = acc4[r] + bv + states[o];
    }
  }
}

// ================= launch
extern "C" void kernel_launch(void* const* d_in, const int* in_sizes, int n_in,
                              void* d_out, int out_size, void* d_ws, size_t ws_size,
                              hipStream_t stream) {
  const float* states = (const float*)d_in[0];
  const float* pos    = (const float*)d_in[1];
  const int*   radius = (const int*)d_in[2];
  const float* W1 = (const float*)d_in[3];
  const float* b1 = (const float*)d_in[4];
  const float* W2 = (const float*)d_in[5];
  const float* b2 = (const float*)d_in[6];
  const float* W3 = (const float*)d_in[7];
  const float* b3 = (const float*)d_in[8];
  const float* W4 = (const float*)d_in[9];
  const float* b4 = (const float*)d_in[10];
  const float* W5 = (const float*)d_in[11];
  const float* b5 = (const float*)d_in[12];
  const float* W6 = (const float*)d_in[13];
  const float* b6 = (const float*)d_in[14];
  float* out = (float*)d_out;

  u16* ws16 = (u16*)d_ws;
  u16* msgs  = ws16;                           // [ROWS][64] orig order
  u16* aggr  = msgs + (size_t)ROWS * 64;       // [ROWS][64] orig order
  u16* msgsT = aggr + (size_t)ROWS * 64;       // [NB][64][NAG] channel-major sorted
  u16* wts   = msgsT + (size_t)ROWS * 64;      // 49152 u16
  char* pbyte = (char*)(wts + 49152);
  float2* pos_sorted = (float2*)pbyte;                  // ROWS float2
  int* cell_start = (int*)(pbyte + (size_t)ROWS * 8);   // NB*CSTRIDE
  int* sid  = cell_start + NB * CSTRIDE;                // ROWS
  int* invp = sid + ROWS;                               // ROWS

  constexpr int LDS_K1 = 26624 * 2;                       // 53248
  constexpr int LDS_K3 = (384 * 136 + 8 * 16 * 136) * 2;  // 139264

  bin_kernel<<<NB, 1024, 0, stream>>>(pos, pos_sorted, cell_start, sid, invp);

  mlp1_kernel<<<260, 1024, LDS_K1, stream>>>(
      states, W1, b1, W2, b2, W3, W4, W5, W6, invp, wts, msgs, msgsT);

  agg_kernel<<<dim3(NAG / 64, NB), 256, 0, stream>>>(
      pos_sorted, msgsT, cell_start, sid, radius, aggr);

  mlp23_kernel<<<256, 1024, LDS_K3, stream>>>(
      states, msgs, aggr, wts, b3, b4, b5, b6, out);
}

// Round 15
// 40.295 us; speedup vs baseline: 1.8553x; 1.8553x over previous
//
#include <hip/hip_runtime.h>

typedef unsigned short u16;
typedef unsigned int u32;
typedef __bf16 bf16x8 __attribute__((ext_vector_type(8)));
typedef unsigned short ushort8 __attribute__((ext_vector_type(8)));
typedef float f32x4 __attribute__((ext_vector_type(4)));

#define DEV_INLINE __device__ __forceinline__

constexpr int NB = 4;
constexpr int NAG = 4096;
constexpr int ROWS = NB * NAG;
constexpr int GRID = 20;
constexpr int CELLS = GRID * GRID;
constexpr int CSTRIDE = 404;
constexpr int MAXNB = 128;

DEV_INLINE u16 f2bu(float x) { __bf16 h = (__bf16)x; return __builtin_bit_cast(u16, h); }
DEV_INLINE float bu2f(u16 u) { return __builtin_bit_cast(float, ((u32)u) << 16); }
DEV_INLINE u32 pack2(float a, float b) { return (u32)f2bu(a) | ((u32)f2bu(b) << 16); }

DEV_INLINE f32x4 MF(bf16x8 a, const u16* p, f32x4 c) {
  ushort8 bu = *(const ushort8*)p;
  return __builtin_amdgcn_mfma_f32_16x16x32_bf16(a, __builtin_bit_cast(bf16x8, bu), c, 0, 0, 0);
}

template<bool BF>
DEV_INLINE bf16x8 loadA(const void* __restrict__ src, int row, int c) {
  if constexpr (BF) {
    ushort8 u = *reinterpret_cast<const ushort8*>((const u16*)src + (size_t)row * 64 + c);
    return __builtin_bit_cast(bf16x8, u);
  } else {
    const float* f = (const float*)src + (size_t)row * 64 + c;
    f32x4 a = *(const f32x4*)f;
    f32x4 b = *(const f32x4*)(f + 4);
    bf16x8 r;
    r[0] = (__bf16)a[0]; r[1] = (__bf16)a[1]; r[2] = (__bf16)a[2]; r[3] = (__bf16)a[3];
    r[4] = (__bf16)b[0]; r[5] = (__bf16)b[1]; r[6] = (__bf16)b[2]; r[7] = (__bf16)b[3];
    return r;
  }
}

// ================= K1: binning (blocks 0..3) | mlp1 (4..259) | W3-6 transpose (260..263)
// (verbatim from round 9/11)
__global__ __launch_bounds__(1024) void fused_setup_mlp1(
    const float* __restrict__ pos, const float* __restrict__ states,
    const float* __restrict__ W1, const float* __restrict__ b1,
    const float* __restrict__ W2, const float* __restrict__ b2,
    const float* __restrict__ W3, const float* __restrict__ W4,
    const float* __restrict__ W5, const float* __restrict__ W6,
    u16* __restrict__ wts, u16* __restrict__ msgs,
    float2* __restrict__ pos_sorted, int* __restrict__ cell_start,
    int* __restrict__ sid)
{
  extern __shared__ u16 smem[];
  const int tid = threadIdx.x;
  const int lane = tid & 63;
  const int wave = tid >> 6;
  const int bid = blockIdx.x;

  if (bid < NB) {
    int* cnt_s = (int*)smem;
    int* start_s = cnt_s + CELLS;
    u16* cell_of = (u16*)(start_s + CELLS + 1);
    u16* rank_of = cell_of + NAG;
    const float2* pb = (const float2*)(pos + (size_t)bid * NAG * 2);
    for (int c = tid; c < CELLS; c += 1024) cnt_s[c] = 0;
    __syncthreads();
    for (int i = tid; i < NAG; i += 1024) {
      float2 p = pb[i];
      int cx = min(max((int)floorf(p.x), 0), GRID - 1);
      int cy = min(max((int)floorf(p.y), 0), GRID - 1);
      int c = cy * GRID + cx;
      rank_of[i] = (u16)atomicAdd(&cnt_s[c], 1);
      cell_of[i] = (u16)c;
    }
    __syncthreads();
    if (wave == 0) {
      int carry = 0;
      for (int g = 0; g < CELLS; g += 64) {
        int c = g + lane;
        int x = (c < CELLS) ? cnt_s[c] : 0;
#pragma unroll
        for (int off = 1; off < 64; off <<= 1) {
          int y = __shfl_up(x, off, 64);
          if (lane >= off) x += y;
        }
        if (c < CELLS) start_s[c + 1] = carry + x;
        carry += __shfl(x, 63, 64);
      }
      if (lane == 0) start_s[0] = 0;
    }
    __syncthreads();
    for (int c = tid; c <= CELLS; c += 1024) cell_start[bid * CSTRIDE + c] = start_s[c];
    for (int i = tid; i < NAG; i += 1024) {
      int kk = start_s[cell_of[i]] + (int)rank_of[i];
      sid[bid * NAG + kk] = bid * NAG + i;
      pos_sorted[bid * NAG + kk] = pb[i];
    }
    return;
  }

  if (bid >= NB + 256) {
    const int base = (bid - (NB + 256)) * 12288;
#pragma unroll
    for (int t = 0; t < 12; ++t) {
      int idx = base + t * 1024 + tid;
      const float* src; int n, k, Nc;
      if (idx < 16384)      { src = W3; n = idx >> 7; k = idx & 127; Nc = 128; }
      else if (idx < 24576) { int li = idx - 16384; src = W4; n = li >> 7; k = li & 127; Nc = 64; }
      else if (idx < 40960) { int li = idx - 24576; src = W5; n = li >> 7; k = li & 127; Nc = 128; }
      else                  { int li = idx - 40960; src = W6; n = li >> 7; k = li & 127; Nc = 64; }
      wts[idx] = f2bu(src[k * Nc + n]);
    }
    return;
  }

  // ---------- mlp1 ----------
  u16* WaTs = smem;              // [128][72]
  u16* WbTs = smem + 9216;       // [64][136]
  u16* ovl  = smem + 17920;      // overlay

  const int l15 = lane & 15;
  const int khalf = (lane >> 4) * 8;
  const int rg = wave >> 2;
  const int cq = wave & 3;
  const int rb = (bid - NB) * 64 + rg * 16;
  const int row = rb + l15;

  bf16x8 aS[2];
  aS[0] = loadA<false>(states, row, khalf);
  aS[1] = loadA<false>(states, row, 32 + khalf);

  for (int t = tid; t < 4096; t += 1024) {
    const int e = t * 2;
    const int k = e >> 7, n = e & 127;
    const float2 v = *(const float2*)&W1[e];
    *(u32*)&ovl[k * 132 + n] = pack2(v.x, v.y);
  }
  __syncthreads();
  {
    const int n = tid & 127, g = tid >> 7;
    ushort8 v;
#pragma unroll
    for (int j = 0; j < 8; ++j) v[j] = ovl[(g * 8 + j) * 132 + n];
    *(ushort8*)&WaTs[n * 72 + g * 8] = v;
  }
  __syncthreads();
  for (int t = tid; t < 4096; t += 1024) {
    const int e = t * 2;
    const int k = e >> 6, n = e & 63;
    const float2 v = *(const float2*)&W2[e];
    *(u32*)&ovl[k * 68 + n] = pack2(v.x, v.y);
  }
  __syncthreads();
  {
    const int n = tid & 63, g = tid >> 6;
    ushort8 v;
#pragma unroll
    for (int j = 0; j < 8; ++j) v[j] = ovl[(g * 8 + j) * 68 + n];
    *(ushort8*)&WbTs[n * 136 + g * 8] = v;
  }
  __syncthreads();

  u16* hs = ovl + rg * 2176;

  f32x4 acc1[2] = {};
#pragma unroll
  for (int kt = 0; kt < 2; ++kt) {
#pragma unroll
    for (int j = 0; j < 2; ++j) {
      const int nt = cq * 2 + j;
      acc1[j] = MF(aS[kt], &WaTs[(nt * 16 + l15) * 72 + kt * 32 + khalf], acc1[j]);
    }
  }
#pragma unroll
  for (int j = 0; j < 2; ++j) {
    const int col = (cq * 2 + j) * 16 + l15;
    const float bv = b1[col];
#pragma unroll
    for (int r = 0; r < 4; ++r)
      hs[((lane >> 4) * 4 + r) * 136 + col] = f2bu(fmaxf(acc1[j][r] + bv, 0.0f));
  }
  __syncthreads();

  f32x4 acc2 = {};
#pragma unroll
  for (int kt = 0; kt < 4; ++kt) {
    ushort8 au = *(const ushort8*)&hs[l15 * 136 + kt * 32 + khalf];
    acc2 = MF(__builtin_bit_cast(bf16x8, au),
              &WbTs[(cq * 16 + l15) * 136 + kt * 32 + khalf], acc2);
  }
  {
    const int col = cq * 16 + l15;
    const float bv = b2[col];
#pragma unroll
    for (int r = 0; r < 4; ++r)
      msgs[(size_t)(rb + (lane >> 4) * 4 + r) * 64 + col] = f2bu(acc2[r] + bv);
  }
}

// ================= K2: aggregation — merged-range mask (one full-lane sweep over the
// concatenated 3-row candidate list; candidate order identical to the per-range scan,
// so idxb and all sums are bit-identical to R11) + R11's wide-quad gather.
__global__ __launch_bounds__(256) void agg_kernel(
    const float2* __restrict__ pos_sorted, const u16* __restrict__ msgs,
    const int* __restrict__ cell_start, const int* __restrict__ sid,
    const int* __restrict__ radius_ptr, u16* __restrict__ aggr)
{
  __shared__ u16 idxb[4][MAXNB];
  const int b = blockIdx.y;
  const int lane = threadIdx.x & 63;
  const int wave = threadIdx.x >> 6;
  const int k = blockIdx.x * 4 + wave;
  const float2* pb = pos_sorted + (size_t)b * NAG;
  const float2 pk = pb[k];
  const float r = (float)(*radius_ptr);
  const float r2 = __fmul_rn(r, r);
  const int cx = min(max((int)floorf(pk.x), 0), GRID - 1);
  const int cy = min(max((int)floorf(pk.y), 0), GRID - 1);
  const int* cs = cell_start + b * CSTRIDE;
  const int* sb = sid + b * NAG;
  const unsigned long long lt = (1ull << lane) - 1ull;
  const int x0 = max(cx - 1, 0), x1 = min(cx + 1, GRID - 1);

  // ---- load all range bounds upfront (independent loads, no serial chains) ----
  int cbase[3], clen[3];
#pragma unroll
  for (int dy = 0; dy < 3; ++dy) {
    const int yy = cy + dy - 1;
    int s0 = 0, s1 = 0;
    if (yy >= 0 && yy < GRID) {
      s0 = cs[yy * GRID + x0];
      s1 = cs[yy * GRID + x1 + 1];
    }
    cbase[dy] = s0;
    clen[dy] = s1 - s0;
  }
  const int L0 = clen[0];
  const int L01 = clen[0] + clen[1];
  const int tot = L01 + clen[2];

  // ---- merged mask sweep: 64 lanes over concatenated candidates ----
  int cnt = 0;
  for (int t = 0; t < tot; t += 64) {
    const int g = t + lane;
    const bool inb = g < tot;
    int j;
    if (g < L0)       j = cbase[0] + g;
    else if (g < L01) j = cbase[1] + (g - L0);
    else              j = cbase[2] + (g - L01);
    j = min(j, NAG - 1);                      // safe clamp for masked lanes
    const float2 pj = pb[j];
    const int sbj = sb[j];
    const float dx_ = pk.x - pj.x;
    const float dy_ = pk.y - pj.y;
    const float d2 = __fadd_rn(__fmul_rn(dx_, dx_), __fmul_rn(dy_, dy_));
    const bool ok = inb && (d2 < r2) && (j != k);
    const unsigned long long m = __ballot(ok);
    if (ok) {
      const int p = cnt + __popcll(m & lt);
      if (p < MAXNB) idxb[wave][p] = (u16)sbj;   // ORIGINAL global row
    }
    cnt += (int)__popcll(m);
  }

  // ---- wide-quad gather (R11 verbatim) ----
  const int q = lane & 15;     // channel quad
  const int s = lane >> 4;     // row slot
  const int n = min(cnt, MAXNB);
  float a0 = 0.0f, a1 = 0.0f, a2 = 0.0f, a3 = 0.0f;
  const int nfull = n & ~3;
  for (int g = 0; g < nfull; g += 4) {
    const int jj = (int)idxb[wave][g + s];
    const uint2 v = *(const uint2*)(msgs + (size_t)jj * 64 + q * 4);
    a0 += __builtin_bit_cast(float, v.x << 16);
    a1 += __builtin_bit_cast(float, v.x & 0xffff0000u);
    a2 += __builtin_bit_cast(float, v.y << 16);
    a3 += __builtin_bit_cast(float, v.y & 0xffff0000u);
  }
  const int t = n - nfull;
  if (s < t) {
    const int jj = (int)idxb[wave][nfull + s];
    const uint2 v = *(const uint2*)(msgs + (size_t)jj * 64 + q * 4);
    a0 += __builtin_bit_cast(float, v.x << 16);
    a1 += __builtin_bit_cast(float, v.x & 0xffff0000u);
    a2 += __builtin_bit_cast(float, v.y << 16);
    a3 += __builtin_bit_cast(float, v.y & 0xffff0000u);
  }
  a0 += __shfl_xor(a0, 16); a1 += __shfl_xor(a1, 16);
  a2 += __shfl_xor(a2, 16); a3 += __shfl_xor(a3, 16);
  a0 += __shfl_xor(a0, 32); a1 += __shfl_xor(a1, 32);
  a2 += __shfl_xor(a2, 32); a3 += __shfl_xor(a3, 32);

  if (s == 0) {
    const float inv = 1.0f / (float)(cnt > 0 ? cnt : 1);
    const int orow = sb[k];
    uint2 w;
    w.x = pack2(a0 * inv, a1 * inv);
    w.y = pack2(a2 * inv, a3 * inv);
    *(uint2*)(aggr + (size_t)orow * 64 + q * 4) = w;
  }
}

// ================= K3: fused MLP2+MLP3 (verbatim from round 9/11)
__global__ __launch_bounds__(1024, 4) void mlp23_kernel(
    const float* __restrict__ states, const u16* __restrict__ msgs,
    const u16* __restrict__ aggr, const u16* __restrict__ wts,
    const float* __restrict__ b3, const float* __restrict__ b4,
    const float* __restrict__ b5, const float* __restrict__ b6,
    float* __restrict__ out)
{
  extern __shared__ u16 smem[];
  u16* W3s = smem;
  u16* W4s = W3s + 128 * 136;
  u16* W5s = W4s + 64 * 136;
  u16* W6s = W5s + 128 * 136;
  u16* hsb = W6s + 64 * 136;
  u16* fsb = hsb + 4 * 16 * 136;

  const int tid = threadIdx.x;
  const int lane = tid & 63;
  const int wave = tid >> 6;
  const int rg = wave >> 2;
  const int cq = wave & 3;
  const int l15 = lane & 15;
  const int khalf = (lane >> 4) * 8;
  const int rb = blockIdx.x * 64 + rg * 16;
  const int row = rb + l15;
  u16* hs = hsb + rg * (16 * 136);
  u16* fs = fsb + rg * (16 * 136);

  bf16x8 aM[2], aG[2], aS[2];
  aM[0] = loadA<true>(msgs, row, khalf);
  aM[1] = loadA<true>(msgs, row, 32 + khalf);
  aG[0] = loadA<true>(aggr, row, khalf);
  aG[1] = loadA<true>(aggr, row, 32 + khalf);
  aS[0] = loadA<false>(states, row, khalf);
  aS[1] = loadA<false>(states, row, 32 + khalf);

  for (int t = tid; t < 6144; t += 1024) {
    const int e = t * 8;
    ushort8 v = *(const ushort8*)&wts[e];
    u16* dst;
    if (e < 16384)      dst = &W3s[(e >> 7) * 136 + (e & 127)];
    else if (e < 24576) { int li = e - 16384; dst = &W4s[(li >> 7) * 136 + (li & 127)]; }
    else if (e < 40960) { int li = e - 24576; dst = &W5s[(li >> 7) * 136 + (li & 127)]; }
    else                { int li = e - 40960; dst = &W6s[(li >> 7) * 136 + (li & 127)]; }
    *(ushort8*)dst = v;
  }
  __syncthreads();

  f32x4 acc1[2] = {};
#pragma unroll
  for (int kt = 0; kt < 4; ++kt) {
    bf16x8 a = (kt < 2) ? aM[kt] : aG[kt - 2];
#pragma unroll
    for (int j = 0; j < 2; ++j) {
      const int nt = cq * 2 + j;
      acc1[j] = MF(a, &W3s[(nt * 16 + l15) * 136 + kt * 32 + khalf], acc1[j]);
    }
  }
#pragma unroll
  for (int j = 0; j < 2; ++j) {
    const int col = (cq * 2 + j) * 16 + l15;
    const float bv = b3[col];
#pragma unroll
    for (int r = 0; r < 4; ++r)
      hs[((lane >> 4) * 4 + r) * 136 + col] = f2bu(fmaxf(acc1[j][r] + bv, 0.0f));
  }
  __syncthreads();

  f32x4 acc2 = {};
#pragma unroll
  for (int kt = 0; kt < 4; ++kt) {
    ushort8 au = *(const ushort8*)&hs[l15 * 136 + kt * 32 + khalf];
    acc2 = MF(__builtin_bit_cast(bf16x8, au),
              &W4s[(cq * 16 + l15) * 136 + kt * 32 + khalf], acc2);
  }
  {
    const int col = cq * 16 + l15;
    const float bv = b4[col];
#pragma unroll
    for (int r = 0; r < 4; ++r)
      fs[((lane >> 4) * 4 + r) * 136 + col] = f2bu(acc2[r] + bv);
  }
  __syncthreads();

  f32x4 acc3[2] = {};
#pragma unroll
  for (int kt = 0; kt < 4; ++kt) {
    bf16x8 a;
    if (kt < 2) a = aS[kt];
    else {
      ushort8 au = *(const ushort8*)&fs[l15 * 136 + (kt - 2) * 32 + khalf];
      a = __builtin_bit_cast(bf16x8, au);
    }
#pragma unroll
    for (int j = 0; j < 2; ++j) {
      const int nt = cq * 2 + j;
      acc3[j] = MF(a, &W5s[(nt * 16 + l15) * 136 + kt * 32 + khalf], acc3[j]);
    }
  }
#pragma unroll
  for (int j = 0; j < 2; ++j) {
    const int col = (cq * 2 + j) * 16 + l15;
    const float bv = b5[col];
#pragma unroll
    for (int r = 0; r < 4; ++r)
      hs[((lane >> 4) * 4 + r) * 136 + col] = f2bu(fmaxf(acc3[j][r] + bv, 0.0f));
  }
  __syncthreads();

  f32x4 acc4 = {};
#pragma unroll
  for (int kt = 0; kt < 4; ++kt) {
    ushort8 au = *(const ushort8*)&hs[l15 * 136 + kt * 32 + khalf];
    acc4 = MF(__builtin_bit_cast(bf16x8, au),
              &W6s[(cq * 16 + l15) * 136 + kt * 32 + khalf], acc4);
  }
  {
    const int col = cq * 16 + l15;
    const float bv = b6[col];
#pragma unroll
    for (int r = 0; r < 4; ++r) {
      const int m = (lane >> 4) * 4 + r;
      const size_t o = (size_t)(rb + m) * 64 + col;
      out[o] = acc4[r] + bv + states[o];
    }
  }
}

// ================= launch
extern "C" void kernel_launch(void* const* d_in, const int* in_sizes, int n_in,
                              void* d_out, int out_size, void* d_ws, size_t ws_size,
                              hipStream_t stream) {
  const float* states = (const float*)d_in[0];
  const float* pos    = (const float*)d_in[1];
  const int*   radius = (const int*)d_in[2];
  const float* W1 = (const float*)d_in[3];
  const float* b1 = (const float*)d_in[4];
  const float* W2 = (const float*)d_in[5];
  const float* b2 = (const float*)d_in[6];
  const float* W3 = (const float*)d_in[7];
  const float* b3 = (const float*)d_in[8];
  const float* W4 = (const float*)d_in[9];
  const float* b4 = (const float*)d_in[10];
  const float* W5 = (const float*)d_in[11];
  const float* b5 = (const float*)d_in[12];
  const float* W6 = (const float*)d_in[13];
  const float* b6 = (const float*)d_in[14];
  float* out = (float*)d_out;

  u16* ws16 = (u16*)d_ws;
  u16* msgs = ws16;
  u16* aggr = msgs + (size_t)ROWS * 64;
  u16* wts  = aggr + (size_t)ROWS * 64;
  char* pbyte = (char*)(wts + 49152);
  float2* pos_sorted = (float2*)pbyte;
  int* cell_start = (int*)(pbyte + (size_t)ROWS * 8);
  int* sid = cell_start + NB * CSTRIDE;

  constexpr int LDS_K1 = 26624 * 2;
  constexpr int LDS_K3 = (384 * 136 + 8 * 16 * 136) * 2;

  fused_setup_mlp1<<<NB + 256 + 4, 1024, LDS_K1, stream>>>(
      pos, states, W1, b1, W2, b2, W3, W4, W5, W6,
      wts, msgs, pos_sorted, cell_start, sid);

  agg_kernel<<<dim3(NAG / 4, NB), 256, 0, stream>>>(
      pos_sorted, msgs, cell_start, sid, radius, aggr);

  mlp23_kernel<<<ROWS / 64, 1024, LDS_K3, stream>>>(
      states, msgs, aggr, wts, b3, b4, b5, b6, out);
}